// Round 6
// baseline (2929.582 us; speedup 1.0000x reference)
//
#include <hip/hip_runtime.h>
#include <hip/hip_cooperative_groups.h>

namespace cg = cooperative_groups;

// MetaOptNet head: 15-iteration IPM QP (block-diagonal: 10x 150x150) + logits.
// Round 6: single cooperative kernel for the whole QP loop (10 blocks, grid.sync),
// proven 8x8-tile 2-barrier pipelined blocked GJ core, all small vectors LDS-resident.
// Deterministic (only u32 atomicMin used; all float reductions fixed-order).

#define NW    10
#define NSH   15
#define NSUP  150
#define NQ    8192
#define DIM   1024
#define NVAR  1500
#define NP    152          // padded matrix dim (identity padding)
#define NTT   19           // 8x8 tiles per dim
#define NACT  (NTT*NTT)    // 361 active threads
#define TPB   384
#define SIGMA 0.1f
#define PSTR  68           // LDS panel row stride (64 + 4 pad)

// ws offsets (floats)
#define OFF_K     0        // K stored [150][NP]
#define OFF_Z     22800
#define OFF_S     24300
#define OFF_LAM   25800
#define OFF_NU    27300
#define OFF_PART  31952    // 10 per-way partial dots for mu
#define OFF_ALPHA 32257    // u32 slot
#define OFF_LP    32260    // 2048 loss partials
#define OFF_WT    34308    // 10x1024
#define OFF_G     44548    // G[i*10+a] = (X_a r1_a)_i
#define OFF_X     69152    // 10 x 152x152 inverses
#define XSZ       (NP*NP)  // 23104

// ---------------- 2-barrier pipelined blocked GJ (19 rank-8 steps) -------------------
// Caller must: build H, store prologue panels (tr==0 -> rowbuf[tc], tc==0 -> colbuf[0][tr]),
// then __syncthreads(), then call. Exits after a barrier with H = inverse tile.
__device__ __forceinline__ void bgj_core(float (&H)[8][8], const int t, const int tr, const int tc,
                                         float (*rowbuf)[PSTR], float (*colbuf)[NTT][PSTR],
                                         float (*wbuf)[PSTR]) {
  const int lane = t & 63;
  const int pr = lane >> 3, pc = lane & 7;
  const int r8 = t & 7;
  const int wj2 = t >> 3;
  const int jb = wj2 >> 1;
  const int jh4 = (wj2 & 1) << 2;        // 0 or 4
  const bool wact = (t < 8*NTT*2);       // 304 threads for W phase
  const bool act = (t < NACT);
  for (int kb = 0; kb < NTT; ++kb) {
    const int cur = kb & 1, nxt = cur ^ 1;
    // ---- per-wave redundant 8x8 pivot inversion ----
    float p = rowbuf[kb][lane];
#pragma unroll
    for (int pp = 0; pp < 8; ++pp) {
      const float pv   = __shfl(p, pp*9, 64);
      const float d    = 1.0f / pv;
      const float rowv = __shfl(p, pp*8 + pc, 64);
      const float colv = __shfl(p, pr*8 + pp, 64);
      const float nr   = rowv * d;
      float v = fmaf(-colv, nr, p);
      if (pr == pp) v = nr;
      if (pc == pp) v = -colv * d;
      if (pr == pp && pc == pp) v = d;
      p = v;
    }
    float pv8[8];                        // Pinv[r8][q]
#pragma unroll
    for (int q = 0; q < 8; ++q) pv8[q] = __shfl(p, r8*8 + q, 64);
    // ---- W = Pinv * rowpanel (4 cols per thread) ----
    if (wact) {
      float w0, w1, w2, w3;
      if (jb == kb) {
        w0 = jh4 ? pv8[4] : pv8[0]; w1 = jh4 ? pv8[5] : pv8[1];
        w2 = jh4 ? pv8[6] : pv8[2]; w3 = jh4 ? pv8[7] : pv8[3];
      } else {
        w0 = w1 = w2 = w3 = 0.0f;
#pragma unroll
        for (int q = 0; q < 8; ++q) {
          const float4 x = *(const float4*)(&rowbuf[jb][q*8 + jh4]);
          w0 = fmaf(pv8[q], x.x, w0); w1 = fmaf(pv8[q], x.y, w1);
          w2 = fmaf(pv8[q], x.z, w2); w3 = fmaf(pv8[q], x.w, w3);
        }
      }
      *(float4*)(&wbuf[jb][r8*8 + jh4]) = make_float4(w0, w1, w2, w3);
    }
    __syncthreads();                     // B1: wbuf ready
    if (act) {
      if (tr == kb) {                    // row panel: H = W
        const float4* wsrc = (const float4*)(&wbuf[tc][0]);
#pragma unroll
        for (int r = 0; r < 8; ++r) {
          const float4 x = wsrc[2*r], y = wsrc[2*r+1];
          H[r][0]=x.x; H[r][1]=x.y; H[r][2]=x.z; H[r][3]=x.w;
          H[r][4]=y.x; H[r][5]=y.y; H[r][6]=y.z; H[r][7]=y.w;
        }
      } else {
        float C[8][8];
        const float4* cs = (const float4*)(&colbuf[cur][tr][0]);
#pragma unroll
        for (int r = 0; r < 8; ++r) {
          const float4 x = cs[2*r], y = cs[2*r+1];
          C[r][0]=x.x; C[r][1]=x.y; C[r][2]=x.z; C[r][3]=x.w;
          C[r][4]=y.x; C[r][5]=y.y; C[r][6]=y.z; C[r][7]=y.w;
        }
        if (tc == kb) {                  // col panel: H = -C*Pinv (zero + update)
#pragma unroll
          for (int r = 0; r < 8; ++r)
#pragma unroll
            for (int c = 0; c < 8; ++c) H[r][c] = 0.0f;
        }
        const float4* wsrc = (const float4*)(&wbuf[tc][0]);
#pragma unroll
        for (int q = 0; q < 8; ++q) {
          const float4 x = wsrc[2*q], y = wsrc[2*q+1];
          const float w0=x.x,w1=x.y,w2=x.z,w3=x.w,w4=y.x,w5=y.y,w6=y.z,w7=y.w;
#pragma unroll
          for (int r = 0; r < 8; ++r) {
            const float cq = C[r][q];
            H[r][0]=fmaf(-cq,w0,H[r][0]); H[r][1]=fmaf(-cq,w1,H[r][1]);
            H[r][2]=fmaf(-cq,w2,H[r][2]); H[r][3]=fmaf(-cq,w3,H[r][3]);
            H[r][4]=fmaf(-cq,w4,H[r][4]); H[r][5]=fmaf(-cq,w5,H[r][5]);
            H[r][6]=fmaf(-cq,w6,H[r][6]); H[r][7]=fmaf(-cq,w7,H[r][7]);
          }
        }
      }
      if (kb < NTT-1) {                  // store next step's panels
        if (tr == kb+1) {
          float4* dst = (float4*)(&rowbuf[tc][0]);
#pragma unroll
          for (int r = 0; r < 8; ++r) {
            dst[2*r]   = make_float4(H[r][0],H[r][1],H[r][2],H[r][3]);
            dst[2*r+1] = make_float4(H[r][4],H[r][5],H[r][6],H[r][7]);
          }
        }
        if (tc == kb+1) {
          float4* dst = (float4*)(&colbuf[nxt][tr][0]);
#pragma unroll
          for (int r = 0; r < 8; ++r) {
            dst[2*r]   = make_float4(H[r][0],H[r][1],H[r][2],H[r][3]);
            dst[2*r+1] = make_float4(H[r][4],H[r][5],H[r][6],H[r][7]);
          }
        }
      }
    }
    __syncthreads();                     // B2: panels for kb+1 ready
  }
}

// ---------------- K = support @ support^T (150x150, stride NP) -----------------------
__global__ __launch_bounds__(256) void k_gram(const float* __restrict__ feat, float* __restrict__ ws) {
  const int bi = blockIdx.x / 10, bj = blockIdx.x % 10;
  const int t = threadIdx.x;
  const int r = t / 15, c = t % 15;
  const bool act = (t < 225);
  __shared__ float As[15][65], Bs[15][65];
  float acc = 0.0f;
  for (int ch = 0; ch < 16; ++ch) {
    for (int idx = t; idx < 960; idx += 256) {
      const int rr = idx >> 6, dd = idx & 63;
      As[rr][dd] = feat[(bi*15+rr)*DIM + ch*64 + dd];
      Bs[rr][dd] = feat[(bj*15+rr)*DIM + ch*64 + dd];
    }
    __syncthreads();
    if (act) {
      for (int dd = 0; dd < 64; ++dd) acc += As[r][dd] * Bs[c][dd];
    }
    __syncthreads();
  }
  if (act) ws[OFF_K + (bi*15+r)*NP + (bj*15+c)] = acc;
}

// ---------------- cooperative QP loop: init + 15 iters + Wt --------------------------
__global__ __launch_bounds__(TPB, 2) void kqp_coop(const int* __restrict__ labSup,
                                                   const float* __restrict__ feat,
                                                   const float* __restrict__ scale,
                                                   float* __restrict__ ws) {
  cg::grid_group grid = cg::this_grid();
  const int b = blockIdx.x;              // way
  const int t = threadIdx.x;
  const int tr = t / NTT, tc = t % NTT;
  const bool act = (t < NACT);
  __shared__ __align__(16) float rowbuf[NTT][PSTR], colbuf[2][NTT][PSTR], wbuf[NTT][PSTR];
  __shared__ float zloc[NP], dloc[NP], r1loc[NP], dzloc[NP], dlamloc[NP], dnuloc[NP];
  __shared__ float pacc[NP][NTT];
  __shared__ float muSh;
  __shared__ float wred[TPB/64];

  // ---- init (split across blocks) ----
  for (int idx = b*TPB + t; idx < NVAR; idx += NW*TPB) {
    const int i = idx / NW, aa = idx % NW;
    const float y = (labSup[i/NSH] == aa) ? 1.0f : 0.0f;
    ws[OFF_Z+idx]   = 0.1f*y - 1.0f;
    ws[OFF_S+idx]   = 1.0f;
    ws[OFF_LAM+idx] = 1.0f;
  }
  if (b == 0 && t < NSUP) ws[OFF_NU + t] = 0.0f;
  if (t == 0) ws[OFF_PART + b] = 150.0f;   // s=lam=1 -> per-way dot = 150
  __threadfence(); grid.sync(); __threadfence();

  for (int it = 0; it < 15; ++it) {
    // ================= Phase A: r1_b, X_b = H_b^{-1}, G_b =================
    if (t == 0) {
      float sm = 0.0f;
#pragma unroll
      for (int i = 0; i < NW; ++i) sm += ws[OFF_PART + i];
      muSh = sm / (float)NVAR;
    }
    if (b == 0 && t == 0) ((unsigned*)ws)[OFF_ALPHA] = 0x7F800000u;  // +inf reset
    for (int i = t; i < NP; i += TPB) {
      if (i < NSUP) {
        zloc[i] = ws[OFF_Z + i*NW + b];
        dloc[i] = ws[OFF_LAM + i*NW + b] / ws[OFF_S + i*NW + b];
      } else { zloc[i] = 0.0f; dloc[i] = 0.0f; }
    }
    __syncthreads();
    float H[8][8];
    if (act) {
#pragma unroll
      for (int r = 0; r < 8; ++r) {
        const int row = 8*tr + r;
        if (row < NSUP) {
          const float4* ks = (const float4*)(ws + OFF_K + row*NP + 8*tc);
          const float4 x = ks[0], y = ks[1];
          H[r][0]=x.x; H[r][1]=x.y; H[r][2]=x.z; H[r][3]=x.w;
          H[r][4]=y.x; H[r][5]=y.y; H[r][6]=y.z; H[r][7]=y.w;
          if (tc == NTT-1) { H[r][6] = 0.0f; H[r][7] = 0.0f; }   // K pad cols
        } else {
#pragma unroll
          for (int c = 0; c < 8; ++c) H[r][c] = 0.0f;
        }
#pragma unroll
        for (int c = 0; c < 8; ++c) {
          const int col = 8*tc + c;
          if (col == row) H[r][c] += (row < NSUP) ? (10.0f + dloc[row]) : 1.0f;
        }
      }
#pragma unroll
      for (int r = 0; r < 8; ++r) {
        float p = 0.0f;
#pragma unroll
        for (int c = 0; c < 8; ++c) p = fmaf(H[r][c], zloc[8*tc + c], p);
        pacc[8*tr + r][tc] = p;          // (H z) partials
      }
      if (tr == 0) {                     // prologue panels for step 0
        float4* dst = (float4*)(&rowbuf[tc][0]);
#pragma unroll
        for (int r = 0; r < 8; ++r) {
          dst[2*r]   = make_float4(H[r][0],H[r][1],H[r][2],H[r][3]);
          dst[2*r+1] = make_float4(H[r][4],H[r][5],H[r][6],H[r][7]);
        }
      }
      if (tc == 0) {
        float4* dst = (float4*)(&colbuf[0][tr][0]);
#pragma unroll
        for (int r = 0; r < 8; ++r) {
          dst[2*r]   = make_float4(H[r][0],H[r][1],H[r][2],H[r][3]);
          dst[2*r+1] = make_float4(H[r][4],H[r][5],H[r][6],H[r][7]);
        }
      }
    }
    __syncthreads();
    const float mu = muSh;
    if (t < NSUP) {
      float hz = 0.0f;
      for (int q = 0; q < NTT; ++q) hz += pacc[t][q];
      const float qz  = hz - dloc[t]*zloc[t];               // (K + 10I) z
      const float y   = (labSup[t/NSH] == b) ? 1.0f : 0.0f;
      const float svv = ws[OFF_S + t*NW+b], lvv = ws[OFF_LAM + t*NW+b];
      const float rd  = qz - y + lvv + ws[OFF_NU + t];
      const float rc  = svv*lvv - SIGMA*mu;
      r1loc[t] = -rd + rc/svv;
    } else if (t < NP) r1loc[t] = 0.0f;
    bgj_core(H, t, tr, tc, rowbuf, colbuf, wbuf);
    if (act) {
      float* Xb = ws + OFF_X + b*XSZ;
#pragma unroll
      for (int r = 0; r < 8; ++r) {
        float4* dst = (float4*)(Xb + (8*tr+r)*NP + 8*tc);
        dst[0] = make_float4(H[r][0],H[r][1],H[r][2],H[r][3]);
        dst[1] = make_float4(H[r][4],H[r][5],H[r][6],H[r][7]);
      }
#pragma unroll
      for (int r = 0; r < 8; ++r) {
        float p = 0.0f;
#pragma unroll
        for (int c = 0; c < 8; ++c) p = fmaf(H[r][c], r1loc[8*tc+c], p);
        pacc[8*tr+r][tc] = p;            // (X_b r1_b) partials
      }
    }
    __syncthreads();
    if (t < NSUP) {
      float g = 0.0f;
      for (int q = 0; q < NTT; ++q) g += pacc[t][q];
      ws[OFF_G + t*NW + b] = g;
    }
    __threadfence(); grid.sync(); __threadfence();

    // ============ Phase B: S = sum X_a (redundant), dnu, dz_b, dlam_b ============
    if (t < NP) {                        // tloc (reuse zloc) = rp + sum_a G_a
      float v = 0.0f;
      if (t < NSUP) {
        float rp = 0.0f, gs = 0.0f;
#pragma unroll
        for (int a = 0; a < NW; ++a) {
          rp += ws[OFF_Z + t*NW + a];
          gs += ws[OFF_G + t*NW + a];
        }
        v = rp + gs;
      }
      zloc[t] = v;
    }
    if (act) {
      // H currently = X_b (own inverse, still in registers); add the other 9
      for (int a = 0; a < NW; ++a) {
        if (a == b) continue;
        const float* Xa = ws + OFF_X + a*XSZ;
#pragma unroll
        for (int r = 0; r < 8; ++r) {
          const float4* src = (const float4*)(Xa + (8*tr+r)*NP + 8*tc);
          const float4 x = src[0], y = src[1];
          H[r][0]+=x.x; H[r][1]+=x.y; H[r][2]+=x.z; H[r][3]+=x.w;
          H[r][4]+=y.x; H[r][5]+=y.y; H[r][6]+=y.z; H[r][7]+=y.w;
        }
      }
      if (tr == 0) {                     // prologue panels
        float4* dst = (float4*)(&rowbuf[tc][0]);
#pragma unroll
        for (int r = 0; r < 8; ++r) {
          dst[2*r]   = make_float4(H[r][0],H[r][1],H[r][2],H[r][3]);
          dst[2*r+1] = make_float4(H[r][4],H[r][5],H[r][6],H[r][7]);
        }
      }
      if (tc == 0) {
        float4* dst = (float4*)(&colbuf[0][tr][0]);
#pragma unroll
        for (int r = 0; r < 8; ++r) {
          dst[2*r]   = make_float4(H[r][0],H[r][1],H[r][2],H[r][3]);
          dst[2*r+1] = make_float4(H[r][4],H[r][5],H[r][6],H[r][7]);
        }
      }
    }
    __syncthreads();
    bgj_core(H, t, tr, tc, rowbuf, colbuf, wbuf);   // H = S^{-1}
    if (act) {
#pragma unroll
      for (int r = 0; r < 8; ++r) {
        float p = 0.0f;
#pragma unroll
        for (int c = 0; c < 8; ++c) p = fmaf(H[r][c], zloc[8*tc+c], p);
        pacc[8*tr+r][tc] = p;
      }
    }
    __syncthreads();
    if (t < NP) {
      float v = 0.0f;
      if (t < NSUP) for (int q = 0; q < NTT; ++q) v += pacc[t][q];
      dnuloc[t] = v;
      dloc[t] = (t < NSUP) ? (r1loc[t] - v) : 0.0f;   // vloc (reuse dloc)
    }
    __syncthreads();
    if (act) {                           // dz_b = X_b * vloc (X_b from L2)
      const float* Xb = ws + OFF_X + b*XSZ;
      const int cb = 8*tc;
#pragma unroll
      for (int r = 0; r < 8; ++r) {
        const float4* src = (const float4*)(Xb + (8*tr+r)*NP + cb);
        const float4 v0 = src[0], v1 = src[1];
        pacc[8*tr+r][tc] =
            v0.x*dloc[cb+0] + v0.y*dloc[cb+1] + v0.z*dloc[cb+2] + v0.w*dloc[cb+3]
          + v1.x*dloc[cb+4] + v1.y*dloc[cb+5] + v1.z*dloc[cb+6] + v1.w*dloc[cb+7];
      }
    }
    __syncthreads();
    if (t < NSUP) {
      float dzv = 0.0f;
      for (int q = 0; q < NTT; ++q) dzv += pacc[t][q];
      const float svv = ws[OFF_S + t*NW+b], lvv = ws[OFF_LAM + t*NW+b];
      const float rc  = svv*lvv - SIGMA*mu;
      const float dlv = (lvv*dzv - rc)/svv;
      dzloc[t] = dzv; dlamloc[t] = dlv;
      unsigned* slot = (unsigned*)ws + OFF_ALPHA;
      const float dsv = -dzv;
      if (dsv < 0.0f) atomicMin(slot, __float_as_uint(-svv/dsv));
      if (dlv < 0.0f) atomicMin(slot, __float_as_uint(-lvv/dlv));
    }
    grid.sync();

    // ================= Phase C: step, partial mu, nu =================
    const unsigned au = __hip_atomic_load((unsigned*)ws + OFF_ALPHA,
                                          __ATOMIC_RELAXED, __HIP_MEMORY_SCOPE_AGENT);
    const float alpha = fminf(1.0f, 0.99f * __uint_as_float(au));
    float part = 0.0f;
    if (t < NSUP) {
      const int idx = t*NW + b;
      const float dzv = dzloc[t], dlv = dlamloc[t];
      const float zn = ws[OFF_Z + idx]   + alpha*dzv;
      const float sn = ws[OFF_S + idx]   - alpha*dzv;
      const float ln = ws[OFF_LAM + idx] + alpha*dlv;
      ws[OFF_Z+idx]=zn; ws[OFF_S+idx]=sn; ws[OFF_LAM+idx]=ln;
      part = sn*ln;
    }
    if (b == 0 && t < NSUP) ws[OFF_NU + t] += alpha * dnuloc[t];
#pragma unroll
    for (int off = 32; off > 0; off >>= 1) part += __shfl_xor(part, off, 64);
    if ((t & 63) == 0) wred[t >> 6] = part;
    __syncthreads();
    if (t == 0) {
      float s = 0.0f;
#pragma unroll
      for (int w2 = 0; w2 < TPB/64; ++w2) s += wred[w2];
      ws[OFF_PART + b] = s;
    }
    __threadfence(); grid.sync(); __threadfence();
  }

  // ---- tail: Wt[b][d] = scale * sum_s support[s][d] * z[s*10+b] ----
  if (t < NSUP) zloc[t] = ws[OFF_Z + t*NW + b];
  __syncthreads();
  const float sc = scale[0];
  for (int d = t; d < DIM; d += TPB) {
    float acc = 0.0f;
    for (int s = 0; s < NSUP; ++s) acc = fmaf(feat[(size_t)s*DIM + d], zloc[s], acc);
    ws[OFF_WT + b*DIM + d] = acc * sc;
  }
}

// ---------------- logits + log_softmax + loss partials (wave per query row) ----------
__global__ __launch_bounds__(256) void k_logits(const float* __restrict__ feat,
                                                const int* __restrict__ labq,
                                                float* __restrict__ out,
                                                float* __restrict__ ws) {
  const int t = threadIdx.x;
  const int wv = t >> 6, l = t & 63;
  const int q = blockIdx.x*4 + wv;
  __shared__ float wtl[NW][DIM];
  __shared__ float lpart[4];
  for (int idx = t; idx < NW*DIM; idx += 256) wtl[idx >> 10][idx & 1023] = ws[OFF_WT + idx];
  __syncthreads();
  const float* qrow = feat + (size_t)(NSUP + q)*DIM;
  float acc[NW];
#pragma unroll
  for (int w = 0; w < NW; ++w) acc[w] = 0.0f;
#pragma unroll
  for (int c = 0; c < 4; ++c) {
    const float4 qv = *(const float4*)(qrow + c*256 + 4*l);
#pragma unroll
    for (int w = 0; w < NW; ++w) {
      const float4 wvv = *(const float4*)(&wtl[w][c*256 + 4*l]);
      acc[w] += qv.x*wvv.x + qv.y*wvv.y + qv.z*wvv.z + qv.w*wvv.w;
    }
  }
#pragma unroll
  for (int w = 0; w < NW; ++w) {
#pragma unroll
    for (int off = 32; off > 0; off >>= 1)
      acc[w] += __shfl_xor(acc[w], off, 64);
  }
  float m = acc[0];
#pragma unroll
  for (int w = 1; w < NW; ++w) m = fmaxf(m, acc[w]);
  float se = 0.0f;
#pragma unroll
  for (int w = 0; w < NW; ++w) se += expf(acc[w]-m);
  const float lse = m + logf(se);
  const int y = labq[q];
  if (l == 0) {
    float lpy = 0.0f;
#pragma unroll
    for (int w = 0; w < NW; ++w) {
      const float lp = acc[w] - lse;
      out[q*NW + w] = lp;
      if (w == y) lpy = lp;
    }
    lpart[wv] = -lpy;
  }
  __syncthreads();
  if (t == 0) ws[OFF_LP + blockIdx.x] = lpart[0]+lpart[1]+lpart[2]+lpart[3];
}

__global__ __launch_bounds__(1024) void k_loss(float* __restrict__ out, const float* __restrict__ ws) {
  const int t = threadIdx.x;
  __shared__ float red[1024];
  red[t] = ws[OFF_LP + t] + ws[OFF_LP + 1024 + t];
  __syncthreads();
  for (int off = 512; off > 0; off >>= 1) {
    if (t < off) red[t] += red[t + off];
    __syncthreads();
  }
  if (t == 0) out[NQ*NW] = red[0] / (float)NQ;
}

extern "C" void kernel_launch(void* const* d_in, const int* in_sizes, int n_in,
                              void* d_out, int out_size, void* d_ws, size_t ws_size,
                              hipStream_t stream) {
  const float* feat  = (const float*)d_in[0];
  const int*   labS  = (const int*)d_in[1];
  const int*   labQ  = (const int*)d_in[2];
  const float* scale = (const float*)d_in[3];
  float* ws  = (float*)d_ws;
  float* out = (float*)d_out;

  k_gram<<<100, 256, 0, stream>>>(feat, ws);

  void* cargs[] = { (void*)&labS, (void*)&feat, (void*)&scale, (void*)&ws };
  hipLaunchCooperativeKernel((void*)kqp_coop, dim3(NW), dim3(TPB), cargs, 0, stream);

  k_logits<<<NQ/4, 256, 0, stream>>>(feat, labQ, out, ws);
  k_loss<<<1, 1024, 0, stream>>>(out, ws);
}

// Round 7
// 2127.388 us; speedup vs baseline: 1.3771x; 1.3771x over previous
//
#include <hip/hip_runtime.h>

// MetaOptNet head: 15-iteration IPM QP (block-diagonal: 10x 150x150) + logits.
// Round 7: 3 launches/iter, no grid.sync. A' = apply-prev-update + invert H_b;
// B' = redundant S-inversion per block + own-way dz/dlam/ratios/dots.
// Proven 8x8-tile 2-barrier pipelined blocked GJ core (round 4).
// Deterministic (u32 atomicMin on positive floats only; fixed-order reductions).

#define NW    10
#define NSH   15
#define NSUP  150
#define NQ    8192
#define DIM   1024
#define NVAR  1500
#define NP    152          // padded matrix dim (identity padding)
#define NTT   19           // 8x8 tiles per dim
#define NACT  (NTT*NTT)    // 361 active threads
#define TPB   384
#define SIGMA 0.1f
#define PSTR  68           // LDS panel row stride (64 + 4 pad)

// ws offsets (floats)
#define OFF_K     0        // K stored [150][NP]
#define OFF_Z     22800    // 1500, layout [i*NW + a]
#define OFF_S     24300
#define OFF_LAM   25800
#define OFF_R1    27300
#define OFF_DZ    28800
#define OFF_DLAM  30300
#define OFF_G     31800    // G[i*10+a] = (X_a r1_a)_i
#define OFF_NU0   33300    // nu ping-pong [2][NP]
#define OFF_NU1   33452
#define OFF_DNU   33604    // 152
#define OFF_DOTS  33756    // 10 x {D0, D1, D2}
#define OFF_MU    33786
#define OFF_SLOT  33788    // 2 u32 alpha slots (ping-pong)
#define OFF_LP    33792    // 2048 loss partials
#define OFF_WT    35840    // 10 x 1024
#define OFF_SMAT  46080    // S = sum_a X_a (152x152)
#define OFF_X     69184    // 10 x 152x152 inverses
#define XSZ       (NP*NP)  // 23104

// ---------------- 2-barrier pipelined blocked GJ (19 rank-8 steps) -------------------
// Caller must: build H, store prologue panels (tr==0 -> rowbuf[tc], tc==0 -> colbuf[0][tr]),
// then __syncthreads(), then call. Exits after a barrier with H = inverse tile.
__device__ __forceinline__ void bgj_core(float (&H)[8][8], const int t, const int tr, const int tc,
                                         float (*rowbuf)[PSTR], float (*colbuf)[NTT][PSTR],
                                         float (*wbuf)[PSTR]) {
  const int lane = t & 63;
  const int pr = lane >> 3, pc = lane & 7;
  const int r8 = t & 7;
  const int wj2 = t >> 3;
  const int jb = wj2 >> 1;
  const int jh4 = (wj2 & 1) << 2;        // 0 or 4
  const bool wact = (t < 8*NTT*2);       // 304 threads for W phase
  const bool act = (t < NACT);
  for (int kb = 0; kb < NTT; ++kb) {
    const int cur = kb & 1, nxt = cur ^ 1;
    // ---- per-wave redundant 8x8 pivot inversion ----
    float p = rowbuf[kb][lane];
#pragma unroll
    for (int pp = 0; pp < 8; ++pp) {
      const float pv   = __shfl(p, pp*9, 64);
      const float d    = 1.0f / pv;
      const float rowv = __shfl(p, pp*8 + pc, 64);
      const float colv = __shfl(p, pr*8 + pp, 64);
      const float nr   = rowv * d;
      float v = fmaf(-colv, nr, p);
      if (pr == pp) v = nr;
      if (pc == pp) v = -colv * d;
      if (pr == pp && pc == pp) v = d;
      p = v;
    }
    float pv8[8];                        // Pinv[r8][q]
#pragma unroll
    for (int q = 0; q < 8; ++q) pv8[q] = __shfl(p, r8*8 + q, 64);
    // ---- W = Pinv * rowpanel (4 cols per thread) ----
    if (wact) {
      float w0, w1, w2, w3;
      if (jb == kb) {
        w0 = jh4 ? pv8[4] : pv8[0]; w1 = jh4 ? pv8[5] : pv8[1];
        w2 = jh4 ? pv8[6] : pv8[2]; w3 = jh4 ? pv8[7] : pv8[3];
      } else {
        w0 = w1 = w2 = w3 = 0.0f;
#pragma unroll
        for (int q = 0; q < 8; ++q) {
          const float4 x = *(const float4*)(&rowbuf[jb][q*8 + jh4]);
          w0 = fmaf(pv8[q], x.x, w0); w1 = fmaf(pv8[q], x.y, w1);
          w2 = fmaf(pv8[q], x.z, w2); w3 = fmaf(pv8[q], x.w, w3);
        }
      }
      *(float4*)(&wbuf[jb][r8*8 + jh4]) = make_float4(w0, w1, w2, w3);
    }
    __syncthreads();                     // B1: wbuf ready
    if (act) {
      if (tr == kb) {                    // row panel: H = W
        const float4* wsrc = (const float4*)(&wbuf[tc][0]);
#pragma unroll
        for (int r = 0; r < 8; ++r) {
          const float4 x = wsrc[2*r], y = wsrc[2*r+1];
          H[r][0]=x.x; H[r][1]=x.y; H[r][2]=x.z; H[r][3]=x.w;
          H[r][4]=y.x; H[r][5]=y.y; H[r][6]=y.z; H[r][7]=y.w;
        }
      } else {
        float C[8][8];
        const float4* cs = (const float4*)(&colbuf[cur][tr][0]);
#pragma unroll
        for (int r = 0; r < 8; ++r) {
          const float4 x = cs[2*r], y = cs[2*r+1];
          C[r][0]=x.x; C[r][1]=x.y; C[r][2]=x.z; C[r][3]=x.w;
          C[r][4]=y.x; C[r][5]=y.y; C[r][6]=y.z; C[r][7]=y.w;
        }
        if (tc == kb) {                  // col panel: H = -C*Pinv (zero + update)
#pragma unroll
          for (int r = 0; r < 8; ++r)
#pragma unroll
            for (int c = 0; c < 8; ++c) H[r][c] = 0.0f;
        }
        const float4* wsrc = (const float4*)(&wbuf[tc][0]);
#pragma unroll
        for (int q = 0; q < 8; ++q) {
          const float4 x = wsrc[2*q], y = wsrc[2*q+1];
          const float w0=x.x,w1=x.y,w2=x.z,w3=x.w,w4=y.x,w5=y.y,w6=y.z,w7=y.w;
#pragma unroll
          for (int r = 0; r < 8; ++r) {
            const float cq = C[r][q];
            H[r][0]=fmaf(-cq,w0,H[r][0]); H[r][1]=fmaf(-cq,w1,H[r][1]);
            H[r][2]=fmaf(-cq,w2,H[r][2]); H[r][3]=fmaf(-cq,w3,H[r][3]);
            H[r][4]=fmaf(-cq,w4,H[r][4]); H[r][5]=fmaf(-cq,w5,H[r][5]);
            H[r][6]=fmaf(-cq,w6,H[r][6]); H[r][7]=fmaf(-cq,w7,H[r][7]);
          }
        }
      }
      if (kb < NTT-1) {                  // store next step's panels
        if (tr == kb+1) {
          float4* dst = (float4*)(&rowbuf[tc][0]);
#pragma unroll
          for (int r = 0; r < 8; ++r) {
            dst[2*r]   = make_float4(H[r][0],H[r][1],H[r][2],H[r][3]);
            dst[2*r+1] = make_float4(H[r][4],H[r][5],H[r][6],H[r][7]);
          }
        }
        if (tc == kb+1) {
          float4* dst = (float4*)(&colbuf[nxt][tr][0]);
#pragma unroll
          for (int r = 0; r < 8; ++r) {
            dst[2*r]   = make_float4(H[r][0],H[r][1],H[r][2],H[r][3]);
            dst[2*r+1] = make_float4(H[r][4],H[r][5],H[r][6],H[r][7]);
          }
        }
      }
    }
    __syncthreads();                     // B2: panels for kb+1 ready
  }
}

// ---------------- K = support @ support^T (150x150, stride NP) -----------------------
__global__ __launch_bounds__(256) void k_gram(const float* __restrict__ feat, float* __restrict__ ws) {
  const int bi = blockIdx.x / 10, bj = blockIdx.x % 10;
  const int t = threadIdx.x;
  const int r = t / 15, c = t % 15;
  const bool act = (t < 225);
  __shared__ float As[15][65], Bs[15][65];
  float acc = 0.0f;
  for (int ch = 0; ch < 16; ++ch) {
    for (int idx = t; idx < 960; idx += 256) {
      const int rr = idx >> 6, dd = idx & 63;
      As[rr][dd] = feat[(bi*15+rr)*DIM + ch*64 + dd];
      Bs[rr][dd] = feat[(bj*15+rr)*DIM + ch*64 + dd];
    }
    __syncthreads();
    if (act) {
      for (int dd = 0; dd < 64; ++dd) acc += As[r][dd] * Bs[c][dd];
    }
    __syncthreads();
  }
  if (act) ws[OFF_K + (bi*15+r)*NP + (bj*15+c)] = acc;
}

// ---- A': apply update(it-1) [or init], r1_b, X_b = H_b^{-1}, G_b = X_b r1_b ---------
__global__ __launch_bounds__(TPB, 2) void kqpA(const int* __restrict__ labSup,
                                               float* __restrict__ ws, const int it) {
  const int b = blockIdx.x;
  const int t = threadIdx.x;
  const int tr = t / NTT, tc = t % NTT;
  const bool act = (t < NACT);
  __shared__ __align__(16) float rowbuf[NTT][PSTR], colbuf[2][NTT][PSTR], wbuf[NTT][PSTR];
  __shared__ float zloc[NP], sloc[NP], lloc[NP], dloc[NP], nuloc[NP], r1loc[NP];
  __shared__ float pacc[NP][NTT];
  unsigned* slots = (unsigned*)ws + OFF_SLOT;
  const int p = it & 1;
  float mu;
  if (it == 0) {
    if (t < NSUP) {
      const float y = (labSup[t/NSH] == b) ? 1.0f : 0.0f;
      const float zv = 0.1f*y - 1.0f;
      zloc[t] = zv; sloc[t] = 1.0f; lloc[t] = 1.0f; nuloc[t] = 0.0f;
      const int idx = t*NW + b;
      ws[OFF_Z+idx] = zv; ws[OFF_S+idx] = 1.0f; ws[OFF_LAM+idx] = 1.0f;
      if (b == 0) ws[OFF_NU1 + t] = 0.0f;           // A'(1) reads parity 1
    } else if (t < NP) { zloc[t]=0.0f; sloc[t]=0.0f; lloc[t]=0.0f; nuloc[t]=0.0f; }
    mu = 1.0f;
    if (t == 0) slots[p] = 0x7F800000u;             // reset slot for B'(0)
    if (b == 0 && t == 0) ws[OFF_MU] = 1.0f;
  } else {
    const float am = __uint_as_float(slots[p^1]);   // written by B'(it-1)
    const float alpha = fminf(1.0f, 0.99f * am);
    if (t == 0) slots[p] = 0x7F800000u;             // reset slot for B'(it)
    float D0 = 0.0f, D1 = 0.0f, D2 = 0.0f;          // mu identity from B'(it-1) dots
#pragma unroll
    for (int a = 0; a < NW; ++a) {
      D0 += ws[OFF_DOTS + a*3 + 0];
      D1 += ws[OFF_DOTS + a*3 + 1];
      D2 += ws[OFF_DOTS + a*3 + 2];
    }
    mu = (D0 + alpha*D1 - alpha*alpha*D2) / (float)NVAR;
    if (b == 0 && t == 0) ws[OFF_MU] = mu;
    const int nuR = OFF_NU0 + p*NP;
    const int nuW = OFF_NU0 + (p^1)*NP;
    if (t < NSUP) {
      const int idx = t*NW + b;
      const float dzv = ws[OFF_DZ + idx], dlv = ws[OFF_DLAM + idx];
      const float zn = ws[OFF_Z + idx]   + alpha*dzv;
      const float sn = ws[OFF_S + idx]   - alpha*dzv;
      const float ln = ws[OFF_LAM + idx] + alpha*dlv;
      ws[OFF_Z+idx]=zn; ws[OFF_S+idx]=sn; ws[OFF_LAM+idx]=ln;
      zloc[t]=zn; sloc[t]=sn; lloc[t]=ln;
      const float nv = ws[nuR + t] + alpha * ws[OFF_DNU + t];
      nuloc[t] = nv;
      if (b == 0) ws[nuW + t] = nv;
    } else if (t < NP) { zloc[t]=0.0f; sloc[t]=0.0f; lloc[t]=0.0f; nuloc[t]=0.0f; }
  }
  __syncthreads();
  if (t < NSUP) dloc[t] = lloc[t] / sloc[t];
  else if (t < NP) dloc[t] = 0.0f;
  __syncthreads();
  float H[8][8];
  if (act) {
#pragma unroll
    for (int r = 0; r < 8; ++r) {
      const int row = 8*tr + r;
      if (row < NSUP) {
        const float4* ks = (const float4*)(ws + OFF_K + row*NP + 8*tc);
        const float4 x = ks[0], y = ks[1];
        H[r][0]=x.x; H[r][1]=x.y; H[r][2]=x.z; H[r][3]=x.w;
        H[r][4]=y.x; H[r][5]=y.y; H[r][6]=y.z; H[r][7]=y.w;
        if (tc == NTT-1) { H[r][6] = 0.0f; H[r][7] = 0.0f; }   // K pad cols
      } else {
#pragma unroll
        for (int c = 0; c < 8; ++c) H[r][c] = 0.0f;
      }
#pragma unroll
      for (int c = 0; c < 8; ++c) {
        const int col = 8*tc + c;
        if (col == row) H[r][c] += (row < NSUP) ? (10.0f + dloc[row]) : 1.0f;
      }
    }
#pragma unroll
    for (int r = 0; r < 8; ++r) {
      float pz = 0.0f;
#pragma unroll
      for (int c = 0; c < 8; ++c) pz = fmaf(H[r][c], zloc[8*tc + c], pz);
      pacc[8*tr + r][tc] = pz;           // (H z) partials
    }
    if (tr == 0) {                       // prologue panels for step 0
      float4* dst = (float4*)(&rowbuf[tc][0]);
#pragma unroll
      for (int r = 0; r < 8; ++r) {
        dst[2*r]   = make_float4(H[r][0],H[r][1],H[r][2],H[r][3]);
        dst[2*r+1] = make_float4(H[r][4],H[r][5],H[r][6],H[r][7]);
      }
    }
    if (tc == 0) {
      float4* dst = (float4*)(&colbuf[0][tr][0]);
#pragma unroll
      for (int r = 0; r < 8; ++r) {
        dst[2*r]   = make_float4(H[r][0],H[r][1],H[r][2],H[r][3]);
        dst[2*r+1] = make_float4(H[r][4],H[r][5],H[r][6],H[r][7]);
      }
    }
  }
  __syncthreads();
  if (t < NSUP) {
    float hz = 0.0f;
    for (int q = 0; q < NTT; ++q) hz += pacc[t][q];
    const float qz  = hz - dloc[t]*zloc[t];          // (K + 10I) z
    const float y   = (labSup[t/NSH] == b) ? 1.0f : 0.0f;
    const float rd  = qz - y + lloc[t] + nuloc[t];   // p = -y
    const float rc  = sloc[t]*lloc[t] - SIGMA*mu;
    const float r1v = -rd + rc/sloc[t];
    ws[OFF_R1 + t*NW + b] = r1v;
    r1loc[t] = r1v;
  } else if (t < NP) r1loc[t] = 0.0f;
  bgj_core(H, t, tr, tc, rowbuf, colbuf, wbuf);
  if (act) {
    float* Xb = ws + OFF_X + b*XSZ;
#pragma unroll
    for (int r = 0; r < 8; ++r) {
      float4* dst = (float4*)(Xb + (8*tr+r)*NP + 8*tc);
      dst[0] = make_float4(H[r][0],H[r][1],H[r][2],H[r][3]);
      dst[1] = make_float4(H[r][4],H[r][5],H[r][6],H[r][7]);
    }
#pragma unroll
    for (int r = 0; r < 8; ++r) {
      float pg = 0.0f;
#pragma unroll
      for (int c = 0; c < 8; ++c) pg = fmaf(H[r][c], r1loc[8*tc+c], pg);
      pacc[8*tr+r][tc] = pg;             // (X_b r1_b) partials
    }
  }
  __syncthreads();
  if (t < NSUP) {
    float g = 0.0f;
    for (int q = 0; q < NTT; ++q) g += pacc[t][q];
    ws[OFF_G + t*NW + b] = g;
  }
}

// ---------------- k_sum: S = sum_a X_a (parallel across CUs) -------------------------
__global__ __launch_bounds__(256) void k_sum(float* __restrict__ ws) {
  for (int idx = blockIdx.x*256 + threadIdx.x; idx < XSZ; idx += gridDim.x*256) {
    float v = 0.0f;
#pragma unroll
    for (int a = 0; a < NW; ++a) v += ws[OFF_X + a*XSZ + idx];
    ws[OFF_SMAT + idx] = v;
  }
}

// ---- B': redundant S-inversion per block; dnu; own-way dz/dlam/ratios/dots ----------
__global__ __launch_bounds__(TPB, 2) void kqpB(float* __restrict__ ws, const int it) {
  const int b = blockIdx.x;
  const int t = threadIdx.x;
  const int tr = t / NTT, tc = t % NTT;
  const bool act = (t < NACT);
  __shared__ __align__(16) float rowbuf[NTT][PSTR], colbuf[2][NTT][PSTR], wbuf[NTT][PSTR];
  __shared__ float tloc[NP], r1l[NP], vloc[NP];
  __shared__ float pacc[NP][NTT];
  __shared__ float wred[TPB/64][3];
  const float mu = ws[OFF_MU];
  if (t < NP) {
    float v = 0.0f;
    if (t < NSUP) {
      float rp = 0.0f, gs = 0.0f;
#pragma unroll
      for (int a = 0; a < NW; ++a) {
        rp += ws[OFF_Z + t*NW + a];
        gs += ws[OFF_G + t*NW + a];
      }
      v = rp + gs;
      r1l[t] = ws[OFF_R1 + t*NW + b];
    } else r1l[t] = 0.0f;
    tloc[t] = v;
  }
  float Sg[8][8];
  if (act) {
#pragma unroll
    for (int r = 0; r < 8; ++r) {
      const float4* ss = (const float4*)(ws + OFF_SMAT + (8*tr+r)*NP + 8*tc);
      const float4 x = ss[0], y = ss[1];
      Sg[r][0]=x.x; Sg[r][1]=x.y; Sg[r][2]=x.z; Sg[r][3]=x.w;
      Sg[r][4]=y.x; Sg[r][5]=y.y; Sg[r][6]=y.z; Sg[r][7]=y.w;
    }
    if (tr == 0) {
      float4* dst = (float4*)(&rowbuf[tc][0]);
#pragma unroll
      for (int r = 0; r < 8; ++r) {
        dst[2*r]   = make_float4(Sg[r][0],Sg[r][1],Sg[r][2],Sg[r][3]);
        dst[2*r+1] = make_float4(Sg[r][4],Sg[r][5],Sg[r][6],Sg[r][7]);
      }
    }
    if (tc == 0) {
      float4* dst = (float4*)(&colbuf[0][tr][0]);
#pragma unroll
      for (int r = 0; r < 8; ++r) {
        dst[2*r]   = make_float4(Sg[r][0],Sg[r][1],Sg[r][2],Sg[r][3]);
        dst[2*r+1] = make_float4(Sg[r][4],Sg[r][5],Sg[r][6],Sg[r][7]);
      }
    }
  }
  __syncthreads();
  bgj_core(Sg, t, tr, tc, rowbuf, colbuf, wbuf);    // Sg = S^{-1}
  if (act) {
#pragma unroll
    for (int r = 0; r < 8; ++r) {
      float pd = 0.0f;
#pragma unroll
      for (int c = 0; c < 8; ++c) pd = fmaf(Sg[r][c], tloc[8*tc+c], pd);
      pacc[8*tr+r][tc] = pd;
    }
  }
  __syncthreads();
  if (t < NP) {
    float v = 0.0f;
    if (t < NSUP) {
      for (int q = 0; q < NTT; ++q) v += pacc[t][q];
      if (b == 0) ws[OFF_DNU + t] = v;              // all blocks compute identical dnu
    }
    vloc[t] = (t < NSUP) ? (r1l[t] - v) : 0.0f;
  }
  __syncthreads();
  if (act) {                                        // dz_b = X_b * vloc (X_b from L2)
    const float* Xb = ws + OFF_X + b*XSZ;
    const int cb = 8*tc;
#pragma unroll
    for (int r = 0; r < 8; ++r) {
      const float4* src = (const float4*)(Xb + (8*tr+r)*NP + cb);
      const float4 v0 = src[0], v1 = src[1];
      pacc[8*tr+r][tc] =
          v0.x*vloc[cb+0] + v0.y*vloc[cb+1] + v0.z*vloc[cb+2] + v0.w*vloc[cb+3]
        + v1.x*vloc[cb+4] + v1.y*vloc[cb+5] + v1.z*vloc[cb+6] + v1.w*vloc[cb+7];
    }
  }
  __syncthreads();
  float d0 = 0.0f, d1 = 0.0f, d2 = 0.0f;
  if (t < NSUP) {
    float dzv = 0.0f;
    for (int q = 0; q < NTT; ++q) dzv += pacc[t][q];
    const int idx = t*NW + b;
    const float svv = ws[OFF_S + idx], lvv = ws[OFF_LAM + idx];
    const float rc  = svv*lvv - SIGMA*mu;
    const float dlv = (lvv*dzv - rc)/svv;
    ws[OFF_DZ + idx]   = dzv;
    ws[OFF_DLAM + idx] = dlv;
    unsigned* slot = (unsigned*)ws + OFF_SLOT + (it & 1);
    const float dsv = -dzv;
    if (dsv < 0.0f) atomicMin(slot, __float_as_uint(-svv/dsv));
    if (dlv < 0.0f) atomicMin(slot, __float_as_uint(-lvv/dlv));
    d0 = svv*lvv;                 // dots for next iter's mu identity
    d1 = svv*dlv - lvv*dzv;
    d2 = dzv*dlv;
  }
#pragma unroll
  for (int off = 32; off > 0; off >>= 1) {
    d0 += __shfl_xor(d0, off, 64);
    d1 += __shfl_xor(d1, off, 64);
    d2 += __shfl_xor(d2, off, 64);
  }
  if ((t & 63) == 0) { wred[t>>6][0]=d0; wred[t>>6][1]=d1; wred[t>>6][2]=d2; }
  __syncthreads();
  if (t == 0) {
    float s0=0.0f, s1=0.0f, s2=0.0f;
#pragma unroll
    for (int w = 0; w < TPB/64; ++w) { s0+=wred[w][0]; s1+=wred[w][1]; s2+=wred[w][2]; }
    ws[OFF_DOTS + b*3 + 0] = s0;
    ws[OFF_DOTS + b*3 + 1] = s1;
    ws[OFF_DOTS + b*3 + 2] = s2;
  }
}

// ---- Wt[w][d] = scale * sum_s support[s][d] * z_final[s*10+w] (applies update 14) ----
__global__ __launch_bounds__(1024) void k_wt(const float* __restrict__ feat,
                                             const float* __restrict__ scale,
                                             float* __restrict__ ws) {
  const int w = blockIdx.x;
  const int dd = threadIdx.x;
  __shared__ float zloc[NSUP];
  const float am = __uint_as_float(((unsigned*)ws)[OFF_SLOT + 0]);  // B'(14): it&1 == 0
  const float alpha = fminf(1.0f, 0.99f * am);
  if (dd < NSUP) {
    const int idx = dd*NW + w;
    zloc[dd] = ws[OFF_Z + idx] + alpha * ws[OFF_DZ + idx];
  }
  __syncthreads();
  float acc = 0.0f;
  for (int ss = 0; ss < NSUP; ++ss)
    acc = fmaf(feat[(size_t)ss*DIM + dd], zloc[ss], acc);
  ws[OFF_WT + w*DIM + dd] = acc * scale[0];
}

// ---------------- logits + log_softmax + loss partials (wave per query row) ----------
__global__ __launch_bounds__(256) void k_logits(const float* __restrict__ feat,
                                                const int* __restrict__ labq,
                                                float* __restrict__ out,
                                                float* __restrict__ ws) {
  const int t = threadIdx.x;
  const int wv = t >> 6, l = t & 63;
  const int q = blockIdx.x*4 + wv;
  __shared__ float wtl[NW][DIM];
  __shared__ float lpart[4];
  for (int idx = t; idx < NW*DIM; idx += 256) wtl[idx >> 10][idx & 1023] = ws[OFF_WT + idx];
  __syncthreads();
  const float* qrow = feat + (size_t)(NSUP + q)*DIM;
  float acc[NW];
#pragma unroll
  for (int w = 0; w < NW; ++w) acc[w] = 0.0f;
#pragma unroll
  for (int c = 0; c < 4; ++c) {
    const float4 qv = *(const float4*)(qrow + c*256 + 4*l);
#pragma unroll
    for (int w = 0; w < NW; ++w) {
      const float4 wvv = *(const float4*)(&wtl[w][c*256 + 4*l]);
      acc[w] += qv.x*wvv.x + qv.y*wvv.y + qv.z*wvv.z + qv.w*wvv.w;
    }
  }
#pragma unroll
  for (int w = 0; w < NW; ++w) {
#pragma unroll
    for (int off = 32; off > 0; off >>= 1)
      acc[w] += __shfl_xor(acc[w], off, 64);
  }
  float m = acc[0];
#pragma unroll
  for (int w = 1; w < NW; ++w) m = fmaxf(m, acc[w]);
  float se = 0.0f;
#pragma unroll
  for (int w = 0; w < NW; ++w) se += expf(acc[w]-m);
  const float lse = m + logf(se);
  const int y = labq[q];
  if (l == 0) {
    float lpy = 0.0f;
#pragma unroll
    for (int w = 0; w < NW; ++w) {
      const float lp = acc[w] - lse;
      out[q*NW + w] = lp;
      if (w == y) lpy = lp;
    }
    lpart[wv] = -lpy;
  }
  __syncthreads();
  if (t == 0) ws[OFF_LP + blockIdx.x] = lpart[0]+lpart[1]+lpart[2]+lpart[3];
}

__global__ __launch_bounds__(1024) void k_loss(float* __restrict__ out, const float* __restrict__ ws) {
  const int t = threadIdx.x;
  __shared__ float red[1024];
  red[t] = ws[OFF_LP + t] + ws[OFF_LP + 1024 + t];
  __syncthreads();
  for (int off = 512; off > 0; off >>= 1) {
    if (t < off) red[t] += red[t + off];
    __syncthreads();
  }
  if (t == 0) out[NQ*NW] = red[0] / (float)NQ;
}

extern "C" void kernel_launch(void* const* d_in, const int* in_sizes, int n_in,
                              void* d_out, int out_size, void* d_ws, size_t ws_size,
                              hipStream_t stream) {
  const float* feat  = (const float*)d_in[0];
  const int*   labS  = (const int*)d_in[1];
  const int*   labQ  = (const int*)d_in[2];
  const float* scale = (const float*)d_in[3];
  float* ws  = (float*)d_ws;
  float* out = (float*)d_out;

  k_gram<<<100, 256, 0, stream>>>(feat, ws);
  for (int it = 0; it < 15; ++it) {
    kqpA<<<NW, TPB, 0, stream>>>(labS, ws, it);
    k_sum<<<32, 256, 0, stream>>>(ws);
    kqpB<<<NW, TPB, 0, stream>>>(ws, it);
  }
  k_wt<<<NW, 1024, 0, stream>>>(feat, scale, ws);
  k_logits<<<NQ/4, 256, 0, stream>>>(feat, labQ, out, ws);
  k_loss<<<1, 1024, 0, stream>>>(out, ws);
}